// Round 3
// baseline (3908.345 us; speedup 1.0000x reference)
//
#include <hip/hip_runtime.h>
#include <hip/hip_cooperative_groups.h>
#include <math.h>

namespace cg = cooperative_groups;

#define Bn 64
#define Sn 512
#define Zn 1024
#define H1n 512
#define H2n 256
#define ZSn (Zn*Sn)

// workspace float offsets
#define OFF_LP1  0          // 1024
#define OFF_VT   1024       // 256*64  (V transposed [h][b], f32 — fallback gemm)
#define OFF_V    17408      // 64*512 (fallback)
#define OFF_W    50176      // 64*512 (fallback)
#define OFF_R    82944      // 64*1024 (fallback)
#define OFF_PM   148480     // fallback M partials / coop pbuf0 (64*512*4)
#define OFF_PS   672768     // fallback S partials / coop pbuf1 (64*512*4)
#define OFF_C    1197056    // per-batch LSE(sl) (64 floats)
#define OFF_VB   1200128    // bf16 V [b][h], 16384 ushorts
#define OFF_KB   1310720    // bf16 K (as ushort), 64 MB
#define NEED_BF16_BYTES ((size_t)OFF_KB*4 + (size_t)Bn*ZSn*2)

#define NINF (-__builtin_inff())

typedef __attribute__((ext_vector_type(8))) short          s16x8;
typedef __attribute__((ext_vector_type(8))) unsigned short u16x8;
typedef __attribute__((ext_vector_type(4))) float          f32x4;

__device__ __forceinline__ float wred_max(float x){
#pragma unroll
  for (int o=32;o;o>>=1) x = fmaxf(x, __shfl_xor(x, o, 64));
  return x;
}
__device__ __forceinline__ float wred_sum(float x){
#pragma unroll
  for (int o=32;o;o>>=1) x += __shfl_xor(x, o, 64);
  return x;
}
__device__ __forceinline__ float lae(float a, float c){
  float m = fmaxf(a,c), n = fminf(a,c);
  return m + log1pf(__expf(n-m));
}
__device__ __forceinline__ float toF(float v){ return v; }
__device__ __forceinline__ float toF(unsigned short v){ return __uint_as_float(((unsigned int)v)<<16); }
__device__ __forceinline__ float bflo(unsigned int u){ return __uint_as_float(u<<16); }
__device__ __forceinline__ float bfhi(unsigned int u){ return __uint_as_float(u & 0xffff0000u); }
__device__ __forceinline__ unsigned short bf16rne(float f){
  unsigned int u = __float_as_uint(f);
  return (unsigned short)((u + 0x7fffu + ((u>>16)&1u)) >> 16);
}
__device__ __forceinline__ unsigned int pack2(float a, float b){
  unsigned int ua = __float_as_uint(a), ub = __float_as_uint(b);
  ua = (ua + 0x7fffu + ((ua>>16)&1u)) >> 16;
  ub = (ub + 0x7fffu + ((ub>>16)&1u)) & 0xffff0000u;
  return ua | ub;
}

// single block: lp1 = log_softmax(prior)
__global__ __launch_bounds__(512) void prep_kernel(const float* __restrict__ prior,
                                                   float* __restrict__ ws){
  __shared__ float red[8];
  int t = threadIdx.x;
  float x0 = prior[t], x1 = prior[t+512];
  float m = wred_max(fmaxf(x0,x1));
  if ((t&63)==0) red[t>>6] = m;
  __syncthreads();
  float M = red[0];
#pragma unroll
  for (int i=1;i<8;i++) M = fmaxf(M, red[i]);
  float e = __expf(x0-M)+__expf(x1-M);
  e = wred_sum(e);
  __syncthreads();
  if ((t&63)==0) red[t>>6] = e;
  __syncthreads();
  float T = 0.f;
#pragma unroll
  for (int i=0;i<8;i++) T += red[i];
  float lse = M + logf(T);
  ws[OFF_LP1 + t]       = x0 - lse;
  ws[OFF_LP1 + t + 512] = x1 - lse;
}

// one block per batch: softmax -> sigmoid MLP -> VT[h][b] f32 (+ bf16 V[b][h])
// also stores c_b = LSE(sl_b) for the coop kernel's normalized-marginal sinkhorn.
__global__ __launch_bounds__(512) void mlp_kernel(const float* __restrict__ sl,
    const float* __restrict__ W1, const float* __restrict__ b1,
    const float* __restrict__ W2, const float* __restrict__ b2,
    float* __restrict__ ws, int wbf){
  __shared__ float p[Sn];
  __shared__ float h1s[H1n];
  __shared__ float red[8];
  int b = blockIdx.x, t = threadIdx.x;
  float x = sl[b*Sn + t];
  float m = wred_max(x);
  if ((t&63)==0) red[t>>6] = m;
  __syncthreads();
  float M = red[0];
#pragma unroll
  for (int i=1;i<8;i++) M = fmaxf(M, red[i]);
  float e = __expf(x-M);
  float es = wred_sum(e);
  __syncthreads();
  if ((t&63)==0) red[t>>6] = es;
  __syncthreads();
  float T = 0.f;
#pragma unroll
  for (int i=0;i<8;i++) T += red[i];
  if (t == 0) ws[OFF_C + b] = M + logf(T);   // LSE(sl_b)
  p[t] = e / T;
  __syncthreads();
  float acc = b1[t];
#pragma unroll 8
  for (int s=0;s<Sn;s++) acc = fmaf(p[s], W1[s*H1n + t], acc);
  h1s[t] = 1.f/(1.f+__expf(-acc));
  __syncthreads();
  if (t < H2n){
    float a2 = b2[t];
#pragma unroll 8
    for (int s=0;s<H1n;s++) a2 = fmaf(h1s[s], W2[s*H2n + t], a2);
    float vv = 1.f/(1.f+__expf(-a2));
    ws[OFF_VT + t*Bn + b] = vv;
    if (wbf) ((unsigned short*)(ws + OFF_VB))[b*H2n + t] = bf16rne(vv);
  }
}

// ---------------- fallback f32 gemm (ws too small for bf16 K) ----------------
template<int BF>
__global__ __launch_bounds__(256,1) void gemm_kernel(const float* __restrict__ Wout,
    const float* __restrict__ bout, const float* __restrict__ ws,
    float* __restrict__ Kf, unsigned int* __restrict__ Kb){
  int zh = blockIdx.x*256 + threadIdx.x;
  const float* __restrict__ VT = ws + OFF_VT;
  float2 acc[Bn];
#pragma unroll
  for (int b=0;b<Bn;b++){ acc[b].x = 0.f; acc[b].y = 0.f; }
  const float2* Wp = (const float2*)Wout;
#pragma unroll 2
  for (int h=0; h<H2n; h++){
    float2 wv = Wp[(size_t)h*(ZSn/2) + zh];
    const float* vh = VT + (h<<6);
#pragma unroll
    for (int b=0;b<Bn;b++){
      acc[b].x = fmaf(vh[b], wv.x, acc[b].x);
      acc[b].y = fmaf(vh[b], wv.y, acc[b].y);
    }
  }
  float2 bb = ((const float2*)bout)[zh];
#pragma unroll
  for (int b=0;b<Bn;b++){
    float ax = acc[b].x + bb.x, ay = acc[b].y + bb.y;
    if (BF){
      Kb[(size_t)b*(ZSn/2) + zh] = pack2(ax, ay);
    } else {
      float2 o; o.x = ax; o.y = ay;
      ((float2*)Kf)[(size_t)b*(ZSn/2) + zh] = o;
    }
  }
}

// ---------------- MFMA gemm: K[b,zs] = sum_h V[b,h]*Wout[h,zs] + bout[zs] ----
__global__ __launch_bounds__(256,3) void gemm_mfma(const float* __restrict__ Wout,
    const float* __restrict__ bout, const float* __restrict__ ws,
    unsigned short* __restrict__ Kb){
  __shared__ unsigned short Vsh[64*264];   // [b][h] bf16, row pad +8
  __shared__ float Bsh[32*65];             // [hh][n] f32, row pad +1
  int t = threadIdx.x;
  int zs0 = blockIdx.x * 64;

  {
    const unsigned short* vsrc = (const unsigned short*)(ws + OFF_VB);
    int vrow = t >> 2, vq = t & 3;
#pragma unroll
    for (int i=0;i<8;i++)
      *(u16x8*)&Vsh[vrow*264 + vq*64 + i*8] = *(const u16x8*)&vsrc[vrow*256 + vq*64 + i*8];
  }

  int w  = t >> 6;
  int l  = t & 63;
  int q  = l & 15;
  int kg = l >> 4;
  int sh = t >> 3, sf = t & 7;

  float bo = bout[zs0 + (w<<4) + q];

  f32x4 acc[4] = {{0.f,0.f,0.f,0.f},{0.f,0.f,0.f,0.f},{0.f,0.f,0.f,0.f},{0.f,0.f,0.f,0.f}};

  const float4* src = (const float4*)(Wout + (size_t)sh * ZSn + zs0);
  float4 ra = src[sf], rb = src[sf+8];

  for (int ks=0; ks<8; ks++){
    __syncthreads();
    {
      float* drow = &Bsh[sh*65 + (sf<<2)];
      drow[0]=ra.x; drow[1]=ra.y; drow[2]=ra.z; drow[3]=ra.w;
      drow[32]=rb.x; drow[33]=rb.y; drow[34]=rb.z; drow[35]=rb.w;
    }
    if (ks < 7){
      const float4* s2 = (const float4*)(Wout + (size_t)((ks+1)*32 + sh) * ZSn + zs0);
      ra = s2[sf]; rb = s2[sf+8];
    }
    __syncthreads();
    float bf[8];
#pragma unroll
    for (int j=0;j<8;j++) bf[j] = Bsh[(kg*8+j)*65 + (w<<4) + q];
    unsigned int pk[4];
#pragma unroll
    for (int j=0;j<4;j++)
      asm("v_cvt_pk_bf16_f32 %0, %1, %2" : "=v"(pk[j]) : "v"(bf[2*j]), "v"(bf[2*j+1]));
    union { unsigned int u[4]; s16x8 v; } bu;
    bu.u[0]=pk[0]; bu.u[1]=pk[1]; bu.u[2]=pk[2]; bu.u[3]=pk[3];
#pragma unroll
    for (int mt=0; mt<4; mt++){
      s16x8 af = *(const s16x8*)&Vsh[(mt*16 + q)*264 + ks*32 + kg*8];
      acc[mt] = __builtin_amdgcn_mfma_f32_16x16x32_bf16(af, bu.v, acc[mt], 0, 0, 0);
    }
  }
#pragma unroll
  for (int mt=0; mt<4; mt++){
#pragma unroll
    for (int r=0; r<4; r++){
      int b = mt*16 + kg*4 + r;
      Kb[(size_t)b*ZSn + zs0 + (w<<4) + q] = bf16rne(acc[mt][r] + bo);
    }
  }
}

// ---------------- persistent cooperative sinkhorn + rejection + output -------
// 256 blocks x 1024 threads, 1 block/CU. Block owns (b = blk>>2, 256 z-rows).
// Wave w owns rows z0+w*16..+15; lane l owns cols 8l..8l+7.
// K chunk lives in 64 VGPRs/thread (packed bf16).
// NUMERICS: sinkhorn runs with NORMALIZED lp2' = sl - LSE(sl) so potentials
// stay O(1) (raw lp2 has mass +LSE(sl) per batch -> potentials drift 6.7/iter
// -> exp-sums underflow to 0 by iter ~10 -> log(0) -> NaN; round-2 failure).
// Row steps are shift-invariant, and accept = lp2 - (v'+Lc') is invariant too,
// so the final result is exactly the reference's. Raw sl only re-enters in the
// output's logaddexp term (pr' + c).
__global__ __launch_bounds__(1024, 4) void coop_sinkhorn(
    const unsigned short* __restrict__ Kb, float* __restrict__ ws,
    const float* __restrict__ sl, float* __restrict__ out){
  __shared__ float msh[16*512];
  __shared__ float lsh[256];
  int t = threadIdx.x;
  int l = t & 63, w = t >> 6;
  int blk = blockIdx.x;
  int b = blk >> 2, zc = blk & 3;
  int z0 = zc << 8;

  // stage K rows into regs: 16 x dwordx4, each wave row = 1024B contiguous
  uint4 kreg[16];
  {
    const uint4* Kp = (const uint4*)Kb;
    size_t rbase = ((size_t)((b<<10) + z0 + (w<<4)))*64 + (size_t)l;
#pragma unroll
    for (int r=0;r<16;r++) kreg[r] = Kp[rbase + (size_t)r*64];
  }
  if (t < 256) lsh[t] = ws[OFF_LP1 + z0 + t];

  float c = ws[OFF_C + b];          // LSE(sl_b)
  float prn[8];                     // normalized lp2' = sl - c
  {
    const float4* p4 = (const float4*)(sl + (b<<9) + (l<<3));
    float4 a = p4[0], d = p4[1];
    prn[0]=a.x-c; prn[1]=a.y-c; prn[2]=a.z-c; prn[3]=a.w-c;
    prn[4]=d.x-c; prn[5]=d.y-c; prn[6]=d.z-c; prn[7]=d.w-c;
  }
  __syncthreads();

  float* pbuf0 = ws + OFF_PM;                 // [64][512][4] chunk sums
  float* pbuf1 = ws + OFF_PM + 64*512*4;
  cg::grid_group grid = cg::this_grid();

  float v[8];
  for (int it=0; it<=10; ++it){
    if (it == 0){
#pragma unroll
      for (int j=0;j<8;j++) v[j]=0.f;
    } else {
      const float* pb = (it & 1) ? pbuf0 : pbuf1;   // read buf[(it-1)&1]
#pragma unroll
      for (int j=0;j<8;j++){
        int s = (l<<3)+j;
        float4 s4 = *(const float4*)(pb + (((size_t)(b<<9)+s)<<2));
        float S = (s4.x + s4.y) + (s4.z + s4.w);
        v[j] = prn[j] - __logf(S);
      }
    }
    // row LSE (shift-free; bounded by normalized marginals) + col partials
    float colT[8];
#pragma unroll
    for (int j=0;j<8;j++) colT[j]=0.f;
#pragma unroll
    for (int r=0;r<16;r++){
      uint4 kv = kreg[r];
      float ex[8];
      ex[0]=__expf(bflo(kv.x)+v[0]); ex[1]=__expf(bfhi(kv.x)+v[1]);
      ex[2]=__expf(bflo(kv.y)+v[2]); ex[3]=__expf(bfhi(kv.y)+v[3]);
      ex[4]=__expf(bflo(kv.z)+v[4]); ex[5]=__expf(bfhi(kv.z)+v[5]);
      ex[6]=__expf(bflo(kv.w)+v[6]); ex[7]=__expf(bfhi(kv.w)+v[7]);
      float s = 0.f;
#pragma unroll
      for (int j=0;j<8;j++) s += ex[j];
      s = wred_sum(s);
      float eu = __expf(lsh[(w<<4)+r] - __logf(s));   // exp(lp1[z] - L)
#pragma unroll
      for (int j=0;j<8;j++) colT[j] = fmaf(ex[j], eu, colT[j]);
    }
    // colS = colT * exp(-v)  ( = sum_z exp(K + u) )
    {
      float4 c0, c1;
      c0.x=colT[0]*__expf(-v[0]); c0.y=colT[1]*__expf(-v[1]);
      c0.z=colT[2]*__expf(-v[2]); c0.w=colT[3]*__expf(-v[3]);
      c1.x=colT[4]*__expf(-v[4]); c1.y=colT[5]*__expf(-v[5]);
      c1.z=colT[6]*__expf(-v[6]); c1.w=colT[7]*__expf(-v[7]);
      float4* d = (float4*)&msh[w*512 + (l<<3)];
      d[0]=c0; d[1]=c1;
    }
    __syncthreads();
    if (t < 512){
      float S = 0.f;
#pragma unroll
      for (int ww=0; ww<16; ww++) S += msh[ww*512 + t];
      float* pw = (it & 1) ? pbuf1 : pbuf0;   // write buf[it&1]
      pw[(((size_t)(b<<9)+t)<<2) + zc] = S;
    }
    __threadfence();
    grid.sync();
  }

  // rejection: dj = lp2' - v - Lc (uniform shift c cancels after -amax)
  float dj[8], ed[8];
  {
    float am = NINF;
#pragma unroll
    for (int j=0;j<8;j++){
      int s = (l<<3)+j;
      float4 s4 = *(const float4*)(pbuf0 + (((size_t)(b<<9)+s)<<2));   // it=10 wrote buf0
      float Lc = __logf((s4.x + s4.y) + (s4.z + s4.w));
      dj[j] = prn[j] - v[j] - Lc;
      am = fmaxf(am, dj[j]);
    }
    am = wred_max(am);
#pragma unroll
    for (int j=0;j<8;j++){ dj[j] -= am; ed[j] = __expf(dj[j]); }
  }
  // final: a = x + dj - L (x = K+v; log_softmax(fixed_p1) = x - L); lk = LSE_s(a)
#pragma unroll
  for (int r=0;r<16;r++){
    uint4 kv = kreg[r];
    float x[8], ex[8];
    x[0]=bflo(kv.x)+v[0]; x[1]=bfhi(kv.x)+v[1];
    x[2]=bflo(kv.y)+v[2]; x[3]=bfhi(kv.y)+v[3];
    x[4]=bflo(kv.z)+v[4]; x[5]=bfhi(kv.z)+v[5];
    x[6]=bflo(kv.w)+v[6]; x[7]=bfhi(kv.w)+v[7];
    float s = 0.f, sa = 0.f;
#pragma unroll
    for (int j=0;j<8;j++){
      ex[j] = __expf(x[j]);
      s  += ex[j];
      sa += ex[j]*ed[j];
    }
    s = wred_sum(s); sa = wred_sum(sa);
    float L  = __logf(s);               // row LSE at v10 (= r)
    float lk = __logf(sa) - L;          // log_keep (sa==0 -> -inf -> rs=0, OK)
    float rs = (lk >= 0.f) ? NINF : log1pf(-__expf(lk));
    float l1 = lsh[(w<<4)+r];
    int z = z0 + (w<<4) + r;
    float o[8];
#pragma unroll
    for (int j=0;j<8;j++){
      float a = x[j] + dj[j] - L;
      o[j] = l1 + lae(a, rs + prn[j] + c);
    }
    float4 o0, o1;
    o0.x=o[0]; o0.y=o[1]; o0.z=o[2]; o0.w=o[3];
    o1.x=o[4]; o1.y=o[5]; o1.z=o[6]; o1.w=o[7];
    float4* op = (float4*)(out + (((size_t)(b<<10) + z)<<9) + (l<<3));
    op[0]=o0; op[1]=o1;
  }
}

// ---------------- fallback per-iteration kernels (unchanged) -----------------
template<typename KT>
__global__ __launch_bounds__(512) void iter_fused(const KT* __restrict__ Kg,
    float* __restrict__ ws, const float* __restrict__ sl, int iter, int mode){
  __shared__ KT Ksh[64*512];
  __shared__ float vsh[512];
  __shared__ float ush[64];
  __shared__ float lsh[64];
  int t = threadIdx.x;
  int b = blockIdx.x >> 4, c = blockIdx.x & 15;
  const float4* s4 = (const float4*)(Kg + ((size_t)((b<<10) + (c<<6)) << 9));
  float4* d4 = (float4*)Ksh;
  constexpr int NV = (int)sizeof(KT)*4;
#pragma unroll
  for (int i=0;i<NV;i++) d4[i*512 + t] = s4[i*512 + t];
  if (t < 64) lsh[t] = ws[OFF_LP1 + (c<<6) + t];
  float v_s;
  if (iter == 0) v_s = 0.f;
  else {
    float M = NINF, S = 0.f;
#pragma unroll
    for (int cc=0; cc<16; cc++){
      float m = ws[OFF_PM + ((b*16+cc)<<9) + t];
      float p = ws[OFF_PS + ((b*16+cc)<<9) + t];
      float nm = fmaxf(M, m);
      S = S*__expf(M-nm) + p*__expf(m-nm);
      M = nm;
    }
    v_s = sl[(b<<9) + t] - (M + logf(S));
  }
  vsh[t] = v_s;
  if (mode) ws[OFF_V + (b<<9) + t] = v_s;
  __syncthreads();
  int l = t & 63, w = t >> 6;
  float vr[8];
#pragma unroll
  for (int j=0;j<8;j++) vr[j] = vsh[(l<<3)+j];
#pragma unroll
  for (int rr=0; rr<8; rr++){
    int row = (w<<3) + rr;
    float x[8];
    if constexpr (sizeof(KT)==2){
      u16x8 kv = *(const u16x8*)&Ksh[(row<<9) + (l<<3)];
#pragma unroll
      for (int j=0;j<8;j++) x[j] = toF((unsigned short)kv[j]) + vr[j];
    } else {
      const float4* kp = (const float4*)&Ksh[(row<<9) + (l<<3)];
      float4 k0 = kp[0], k1 = kp[1];
      x[0]=k0.x+vr[0]; x[1]=k0.y+vr[1]; x[2]=k0.z+vr[2]; x[3]=k0.w+vr[3];
      x[4]=k1.x+vr[4]; x[5]=k1.y+vr[5]; x[6]=k1.z+vr[6]; x[7]=k1.w+vr[7];
    }
    float m = NINF;
#pragma unroll
    for (int j=0;j<8;j++) m = fmaxf(m, x[j]);
    m = wred_max(m);
    float s = 0.f;
#pragma unroll
    for (int j=0;j<8;j++) s += __expf(x[j]-m);
    s = wred_sum(s);
    float L = m + logf(s);
    if (l == 0){
      ush[row] = lsh[row] - L;
      if (mode) ws[OFF_R + (b<<10) + (c<<6) + row] = L;
    }
  }
  __syncthreads();
  float M0 = NINF, S0 = 0.f, M1 = NINF, S1 = 0.f;
#pragma unroll 8
  for (int i=0;i<32;i++){
    float xa = toF(Ksh[(i<<9) + t]) + ush[i];
    float na = fmaxf(M0, xa);
    S0 = S0*__expf(M0-na) + __expf(xa-na);
    M0 = na;
    float xb = toF(Ksh[((i+32)<<9) + t]) + ush[i+32];
    float nb = fmaxf(M1, xb);
    S1 = S1*__expf(M1-nb) + __expf(xb-nb);
    M1 = nb;
  }
  float M = fmaxf(M0, M1);
  float S = S0*__expf(M0-M) + S1*__expf(M1-M);
  ws[OFF_PM + ((b*16+c)<<9) + t] = M;
  ws[OFF_PS + ((b*16+c)<<9) + t] = S;
}

__global__ __launch_bounds__(512) void wker(float* __restrict__ ws, const float* __restrict__ sl){
  __shared__ float red[8];
  int b = blockIdx.x, s = threadIdx.x;
  float M = NINF, S = 0.f;
#pragma unroll
  for (int cc=0; cc<16; cc++){
    float m = ws[OFF_PM + ((b*16+cc)<<9) + s];
    float p = ws[OFF_PS + ((b*16+cc)<<9) + s];
    float nm = fmaxf(M, m);
    S = S*__expf(M-nm) + p*__expf(m-nm);
    M = nm;
  }
  float L = M + logf(S);
  float v = ws[OFF_V + (b<<9) + s];
  float araw = sl[(b<<9)+s] - v - L;
  float mm = wred_max(araw);
  if ((s&63)==0) red[s>>6] = mm;
  __syncthreads();
  float amax = red[0];
#pragma unroll
  for (int i=1;i<8;i++) amax = fmaxf(amax, red[i]);
  ws[OFF_W + (b<<9) + s] = v + araw - amax;
}

template<typename KT>
__global__ __launch_bounds__(512) void final_fused(const KT* __restrict__ Kg,
    float* __restrict__ out, const float* __restrict__ ws, const float* __restrict__ sl){
  int t = threadIdx.x, l = t & 63, wv = t >> 6;
  int row = blockIdx.x*8 + wv;
  int b = row >> 10, z = row & (Zn-1);
  const KT* Kr = Kg + ((size_t)row << 9);
  const float* wr = ws + OFF_W + (b << 9);
  const float* pr = sl + (b << 9);
  float r  = ws[OFF_R + row];
  float l1 = ws[OFF_LP1 + z];
  float ww[8], pp[8], kk[8];
  {
    const float4* wp = (const float4*)(wr + (l<<3));
    float4 w0 = wp[0], w1 = wp[1];
    ww[0]=w0.x; ww[1]=w0.y; ww[2]=w0.z; ww[3]=w0.w;
    ww[4]=w1.x; ww[5]=w1.y; ww[6]=w1.z; ww[7]=w1.w;
    const float4* pt = (const float4*)(pr + (l<<3));
    float4 p0 = pt[0], p1 = pt[1];
    pp[0]=p0.x; pp[1]=p0.y; pp[2]=p0.z; pp[3]=p0.w;
    pp[4]=p1.x; pp[5]=p1.y; pp[6]=p1.z; pp[7]=p1.w;
  }
  if constexpr (sizeof(KT)==2){
    u16x8 kv = *(const u16x8*)&Kr[l<<3];
#pragma unroll
    for (int j=0;j<8;j++) kk[j] = toF((unsigned short)kv[j]);
  } else {
    const float4* kp = (const float4*)&Kr[l<<3];
    float4 k0 = kp[0], k1 = kp[1];
    kk[0]=k0.x; kk[1]=k0.y; kk[2]=k0.z; kk[3]=k0.w;
    kk[4]=k1.x; kk[5]=k1.y; kk[6]=k1.z; kk[7]=k1.w;
  }
  float a[8], m = NINF;
#pragma unroll
  for (int j=0;j<8;j++){
    a[j] = kk[j] - r + ww[j];
    m = fmaxf(m, a[j]);
  }
  m = wred_max(m);
  float s = 0.f;
#pragma unroll
  for (int j=0;j<8;j++) s += __expf(a[j]-m);
  s = wred_sum(s);
  float lk = m + logf(s);
  float rs = (lk >= 0.f) ? NINF : log1pf(-__expf(lk));
  float o[8];
#pragma unroll
  for (int j=0;j<8;j++) o[j] = l1 + lae(a[j], rs + pp[j]);
  float4 o0, o1;
  o0.x=o[0]; o0.y=o[1]; o0.z=o[2]; o0.w=o[3];
  o1.x=o[4]; o1.y=o[5]; o1.z=o[6]; o1.w=o[7];
  float4* op = (float4*)(out + ((size_t)row << 9) + (l<<3));
  op[0] = o0; op[1] = o1;
}

extern "C" void kernel_launch(void* const* d_in, const int* in_sizes, int n_in,
                              void* d_out, int out_size, void* d_ws, size_t ws_size,
                              hipStream_t stream) {
  const float* sl    = (const float*)d_in[0];
  const float* W1    = (const float*)d_in[1];
  const float* b1    = (const float*)d_in[2];
  const float* W2    = (const float*)d_in[3];
  const float* b2    = (const float*)d_in[4];
  const float* Wout  = (const float*)d_in[5];
  const float* bout  = (const float*)d_in[6];
  const float* prior = (const float*)d_in[7];
  float* ws = (float*)d_ws;
  float* Kf = (float*)d_out;
  unsigned short* Kb = (unsigned short*)(ws + OFF_KB);
  const bool use_bf16 = (ws_size >= NEED_BF16_BYTES);

  prep_kernel<<<1, 512, 0, stream>>>(prior, ws);
  mlp_kernel<<<Bn, 512, 0, stream>>>(sl, W1, b1, W2, b2, ws, use_bf16 ? 1 : 0);

  if (use_bf16){
    gemm_mfma<<<ZSn/64, 256, 0, stream>>>(Wout, bout, ws, Kb);
    const unsigned short* KbA = Kb;
    float* wsA = ws;
    const float* slA = sl;
    float* outA = (float*)d_out;
    void* args[] = { (void*)&KbA, (void*)&wsA, (void*)&slA, (void*)&outA };
    hipError_t rc = hipLaunchCooperativeKernel((const void*)coop_sinkhorn,
                                               dim3(256), dim3(1024), args, 0, stream);
    if (rc != hipSuccess){
      (void)hipGetLastError();
      for (int it = 0; it < 10; ++it)
        iter_fused<unsigned short><<<Bn*16, 512, 0, stream>>>(Kb, ws, sl, it, 0);
      iter_fused<unsigned short><<<Bn*16, 512, 0, stream>>>(Kb, ws, sl, 10, 1);
      wker<<<Bn, 512, 0, stream>>>(ws, sl);
      final_fused<unsigned short><<<Bn*Zn/8, 512, 0, stream>>>(Kb, (float*)d_out, ws, sl);
    }
  } else {
    gemm_kernel<0><<<ZSn/512, 256, 0, stream>>>(Wout, bout, ws, Kf, nullptr);
    for (int it = 0; it < 10; ++it)
      iter_fused<float><<<Bn*16, 512, 0, stream>>>(Kf, ws, sl, it, 0);
    iter_fused<float><<<Bn*16, 512, 0, stream>>>(Kf, ws, sl, 10, 1);
    wker<<<Bn, 512, 0, stream>>>(ws, sl);
    final_fused<float><<<Bn*Zn/8, 512, 0, stream>>>(Kf, (float*)d_out, ws, sl);
  }
}